// Round 10
// baseline (168.206 us; speedup 1.0000x reference)
//
#include <hip/hip_runtime.h>

// RoutingAttention gfx950 — R19.
// attno occupancy fix: 32-row Q-tiles -> 512 blocks = 2 blocks/CU = 4
// waves/SIMD (was 256 blocks, 1/CU, 2 waves/SIMD — worst-case latency
// hiding for the serial QK->exp->PV chain). Per wave 2 q-groups; oproj
// phase re-tiled 2 row-groups x 4 col-groups. __launch_bounds__(512,4)
// caps VGPR at 128 for guaranteed 2-block residency. LDS 50KB.
// proj (one-launch, top-level mode split) and prep unchanged from R18.
// B=2 P=8 S=1024 C=256 NH=8 DK=32; T=16384.

typedef _Float16 half8 __attribute__((ext_vector_type(8)));
typedef _Float16 half4 __attribute__((ext_vector_type(4)));
typedef float f32x4 __attribute__((ext_vector_type(4)));

#if __has_builtin(__builtin_amdgcn_exp2f)
#define EXP2F(x) __builtin_amdgcn_exp2f(x)
#else
#define EXP2F(x) exp2f(x)
#endif

__device__ __forceinline__ f32x4 mfma16(half8 a, half8 b, f32x4 c) {
  return __builtin_amdgcn_mfma_f32_16x16x32_f16(a, b, c, 0, 0, 0);
}

__device__ __forceinline__ int pk2(float a, float b) {
  auto h = __builtin_amdgcn_cvt_pkrtz(a, b);
  return __builtin_bit_cast(int, h);
}

__device__ __forceinline__ half8 cvt8(float4 f0, float4 f1) {
  union { int i[4]; half8 h; } u;
  u.i[0] = pk2(f0.x, f0.y); u.i[1] = pk2(f0.z, f0.w);
  u.i[2] = pk2(f1.x, f1.y); u.i[3] = pk2(f1.z, f1.w);
  return u.h;
}

__device__ __forceinline__ half8 cvt8v(f32x4 f0, f32x4 f1) {
  union { int i[4]; half8 h; } u;
  u.i[0] = pk2(f0[0], f0[1]); u.i[1] = pk2(f0[2], f0[3]);
  u.i[2] = pk2(f1[0], f1[1]); u.i[3] = pk2(f1[2], f1[3]);
  return u.h;
}

// async global->LDS, 16B per lane; lds dest = wave-uniform base + lane*16
__device__ __forceinline__ void g2lds16(const _Float16* g, _Float16* l) {
  __builtin_amdgcn_global_load_lds(
      (const __attribute__((address_space(1))) void*)g,
      (__attribute__((address_space(3))) void*)l, 16, 0, 0);
}

// ws layout (halves)
static constexpr size_t QH_OFF  = 0;          // (win,s,dk), q scaled log2(e)/sqrt(32)
static constexpr size_t KH_OFF  = 4194304;    // (win,s,dk)
static constexpr size_t VT_OFF  = 8388608;    // (win,dk,s)
static constexpr size_t WF_OFF  = 16777216;   // 4 mats frag-contiguous fp16

// ---------------- W prep: fp32 -> fp16 frag-contiguous ----------------
__global__ __launch_bounds__(256) void prep_kernel(
    const float* __restrict__ wq, const float* __restrict__ wk,
    const float* __restrict__ wv, const float* __restrict__ wo,
    _Float16* __restrict__ ws)
{
  int u = blockIdx.x * 256 + threadIdx.x;          // 0..32767
  int lane = u & 63, ks = (u >> 6) & 7, nt = (u >> 9) & 15, mat = u >> 13;
  const float* W = (mat == 0) ? wq : (mat == 1) ? wk : (mat == 2) ? wv : wo;
  const float* p = W + (size_t)(nt * 16 + (lane & 15)) * 256 + ks * 32 + (lane >> 4) * 8;
  half8 h = cvt8(*(const float4*)p, *(const float4*)(p + 4));
  *(half8*)(ws + WF_OFF + (size_t)u * 8) = h;
}

// ---------------- Q/K/V projection: ONE launch, top-level mode split --------
// mode = blockIdx.y: 0=q, 1=k (row-layout epilogue), 2=v (V^T epilogue).
// Each branch is the verbatim R15-proven single-epilogue pipelined body.
__global__ __launch_bounds__(256, 3) void proj_kernel(
    const float* __restrict__ xq, const float* __restrict__ xk,
    const float* __restrict__ xv,
    const float* __restrict__ bq, const float* __restrict__ bk,
    const float* __restrict__ bv,
    _Float16* __restrict__ ws)
{
  __shared__ __align__(16) _Float16 Wb[16384 + 4608];  // 32KB W stage + 9KB Lt

  int mode = blockIdx.y;
  if (mode < 2) {
    // ================= Q/K body (verbatim R15 qkproj) =================
    _Float16* Lt = Wb + 16384;
    const float* X  = mode ? xk : xq;
    const float* bias = mode ? bk : bq;
    const _Float16* WFm = ws + WF_OFF + (size_t)mode * 65536;
    _Float16* outp = ws + (mode ? KH_OFF : QH_OFF);
    const float scale = mode ? 1.0f : 0.2550348654f;  // log2(e)/sqrt(32)

    int tid = threadIdx.x, lane = tid & 63, wid = tid >> 6;
    int l16 = lane & 15, quad = lane >> 4;
    int m0 = blockIdx.x * 64;
    int b = m0 >> 13, p = (m0 >> 10) & 7, s0 = m0 & 1023;

#pragma unroll
    for (int it = 0; it < 8; ++it)
      g2lds16(WFm + it * 2048 + wid * 512 + lane * 8, Wb + it * 2048 + wid * 512);

    const float* r0 = X + (size_t)(m0 + wid * 16 + l16) * 256 + quad * 8;
    float4 xa[8][2];
#pragma unroll
    for (int ks = 0; ks < 8; ++ks) {
      xa[ks][0] = *(const float4*)(r0 + ks * 32);
      xa[ks][1] = *(const float4*)(r0 + ks * 32 + 4);
    }
    half8 a16[8];
#pragma unroll
    for (int ks = 0; ks < 8; ++ks) a16[ks] = cvt8(xa[ks][0], xa[ks][1]);

    for (int s = 0; s < 4; ++s) {
      __syncthreads();                       // W stage s resident
      f32x4 acc[4] = {};
#pragma unroll
      for (int ks = 0; ks < 8; ++ks)
#pragma unroll
        for (int t = 0; t < 4; ++t) {
          half8 bf = *(const half8*)(Wb + ((size_t)(t * 8 + ks)) * 512 + lane * 8);
          acc[t] = mfma16(a16[ks], bf, acc[t]);
        }
      // Q/K: Lt[row][col], stride 72 halves = 144B (16B-aligned rows)
#pragma unroll
      for (int t = 0; t < 4; ++t) {
        float bval = bias[s * 64 + t * 16 + l16];
#pragma unroll
        for (int r = 0; r < 4; ++r)
          Lt[(wid * 16 + quad * 4 + r) * 72 + t * 16 + l16] =
              (_Float16)((acc[t][r] + bval) * scale);
      }
      __syncthreads();                       // Lt ready AND all waves done w/ Wb
      if (s < 3) {
#pragma unroll
        for (int it = 0; it < 8; ++it)
          g2lds16(WFm + (size_t)(s + 1) * 16384 + it * 2048 + wid * 512 + lane * 8,
                  Wb + it * 2048 + wid * 512);
      }
      // stage s covers out-cols s*64..s*64+63 = heads 2s, 2s+1
#pragma unroll
      for (int j = 0; j < 2; ++j) {
        int chunk = j * 256 + tid;
        int row = chunk >> 3, c8 = chunk & 7;
        half8 v = *(const half8*)(Lt + row * 72 + c8 * 8);
        int h = s * 2 + (c8 >> 2);
        size_t wbase = (size_t)((b * 8 + h) * 8 + p) * 32768;
        *(half8*)(outp + wbase + (size_t)(s0 + row) * 32 + (c8 & 3) * 8) = v;
      }
    }
  } else {
    // ================= V body (verbatim R15 vproj) =================
    _Float16* Lt = Wb + 16384;
    const _Float16* WFm = ws + WF_OFF + (size_t)2 * 65536;
    _Float16* outp = ws + VT_OFF;

    int tid = threadIdx.x, lane = tid & 63, wid = tid >> 6;
    int l16 = lane & 15, quad = lane >> 4;
    int m0 = blockIdx.x * 64;
    int b = m0 >> 13, p = (m0 >> 10) & 7, s0 = m0 & 1023;

#pragma unroll
    for (int it = 0; it < 8; ++it)
      g2lds16(WFm + it * 2048 + wid * 512 + lane * 8, Wb + it * 2048 + wid * 512);

    const float* r0 = xv + (size_t)(m0 + wid * 16 + l16) * 256 + quad * 8;
    float4 xa[8][2];
#pragma unroll
    for (int ks = 0; ks < 8; ++ks) {
      xa[ks][0] = *(const float4*)(r0 + ks * 32);
      xa[ks][1] = *(const float4*)(r0 + ks * 32 + 4);
    }
    half8 a16[8];
#pragma unroll
    for (int ks = 0; ks < 8; ++ks) a16[ks] = cvt8(xa[ks][0], xa[ks][1]);

    for (int s = 0; s < 4; ++s) {
      __syncthreads();                       // W stage s resident
      f32x4 acc[4] = {};
#pragma unroll
      for (int ks = 0; ks < 8; ++ks)
#pragma unroll
        for (int t = 0; t < 4; ++t) {
          half8 bf = *(const half8*)(Wb + ((size_t)(t * 8 + ks)) * 512 + lane * 8);
          acc[t] = mfma16(a16[ks], bf, acc[t]);
        }
      // V^T: Lt[col][row], stride 72 (rows 16B-aligned)
#pragma unroll
      for (int t = 0; t < 4; ++t) {
        float bval = bv[s * 64 + t * 16 + l16];
        half4 h4;
#pragma unroll
        for (int r = 0; r < 4; ++r) h4[r] = (_Float16)(acc[t][r] + bval);
        *(half4*)(Lt + (t * 16 + l16) * 72 + wid * 16 + quad * 4) = h4;
      }
      __syncthreads();                       // Lt ready AND all waves done w/ Wb
      if (s < 3) {
#pragma unroll
        for (int it = 0; it < 8; ++it)
          g2lds16(WFm + (size_t)(s + 1) * 16384 + it * 2048 + wid * 512 + lane * 8,
                  Wb + it * 2048 + wid * 512);
      }
#pragma unroll
      for (int j = 0; j < 2; ++j) {
        int chunk = j * 256 + tid;
        int col = chunk >> 3, r8 = chunk & 7;
        half8 v = *(const half8*)(Lt + col * 72 + r8 * 8);
        int o = s * 64 + col;
        int h = o >> 5, dki = o & 31;
        size_t wbase = (size_t)((b * 8 + h) * 8 + p) * 32768;
        *(half8*)(outp + wbase + (size_t)dki * 1024 + s0 + r8 * 8) = v;
      }
    }
  }
}

// ---------------- fused attention + output projection -----------------------
// Block (b,p,qc32): 32 tokens, 8 waves = 8 heads, full-K per wave.
// 512 blocks = 2 blocks/CU = 4 waves/SIMD (doubled latency hiding vs R18).
// attn: register P-path (permuted K rows, exp2-direct, ones-row lsum),
// 2 q-groups/wave. ctx tile [32][280] fp16 in LDS, then 4-stage streamed-Wo
// oproj (2 row-groups x 4 col-groups) writes fp32 out.
__global__ __launch_bounds__(512, 4) void attno_kernel(
    const _Float16* __restrict__ ws, const float* __restrict__ bo,
    float* __restrict__ out)
{
  __shared__ __align__(16) _Float16 smem[16384 + 8960];  // Wo 32KB + ctx 17.5KB
  _Float16* Wb = smem;
  _Float16* ctxL = smem + 16384;                 // [32][280] halves

  int tid = threadIdx.x, lane = tid & 63, wid = tid >> 6;   // wid = head
  int l16 = lane & 15, quad = lane >> 4;
  int w = blockIdx.x & 15, qc = blockIdx.x >> 4; // XCD-clustered; qc 0..31
  int b = w >> 3, p = w & 7;
  int qrow0 = qc * 32;
  size_t hb = (size_t)((b * 8 + wid) * 8 + p) * 32768;
  const _Float16* qhw = ws + QH_OFF + hb;
  const _Float16* khw = ws + KH_OFF + hb;
  const _Float16* vtw = ws + VT_OFF + hb;
  const _Float16* WF3 = ws + WF_OFF + (size_t)3 * 65536;

  // stage-0 Wo -> LDS, issued first (resident long before oproj phase)
#pragma unroll
  for (int it = 0; it < 4; ++it)
    g2lds16(WF3 + it * 4096 + wid * 512 + lane * 8, Wb + it * 4096 + wid * 512);

  half8 qf[2];
#pragma unroll
  for (int g = 0; g < 2; ++g)
    qf[g] = *(const half8*)(qhw + (size_t)(qrow0 + g * 16 + l16) * 32 + quad * 8);

  // ones A-frag: row m=0 only -> lsum lands in C row 0 (quad==0, reg 0)
  half8 ones = {};
  if (l16 == 0) {
#pragma unroll
    for (int j = 0; j < 8; ++j) ones[j] = (_Float16)1.0f;
  }

  // permuted K row indices: A-row m holds k = (m>>2)*8 + (m&3) (+4 for kc1)
  int kp0 = ((l16 >> 2) << 3) + (l16 & 3);
  int kp1 = kp0 + 4;

  f32x4 Ot[2][2] = {};      // [dk-tile][q-group] O^T partials
  f32x4 Lacc[2] = {};       // lsum via ones-row MFMA

  half8 kc0 = *(const half8*)(khw + (size_t)kp0 * 32 + quad * 8);
  half8 kc1 = *(const half8*)(khw + (size_t)kp1 * 32 + quad * 8);
  half8 vc0 = *(const half8*)(vtw + (size_t)l16 * 1024 + quad * 8);
  half8 vc1 = *(const half8*)(vtw + (size_t)(16 + l16) * 1024 + quad * 8);

  for (int kk = 0; kk < 32; ++kk) {
    int kn = ((kk + 1) & 31) << 5;
    half8 kn0 = *(const half8*)(khw + (size_t)(kn + kp0) * 32 + quad * 8);
    half8 kn1 = *(const half8*)(khw + (size_t)(kn + kp1) * 32 + quad * 8);
    half8 vn0 = *(const half8*)(vtw + (size_t)l16 * 1024 + kn + quad * 8);
    half8 vn1 = *(const half8*)(vtw + (size_t)(16 + l16) * 1024 + kn + quad * 8);

    f32x4 z = {0.f, 0.f, 0.f, 0.f};
#pragma unroll
    for (int g = 0; g < 2; ++g) {
      f32x4 St0 = mfma16(kc0, qf[g], z);
      f32x4 St1 = mfma16(kc1, qf[g], z);
      f32x4 p0, p1;
#pragma unroll
      for (int r = 0; r < 4; ++r) {
        p0[r] = EXP2F(St0[r]);
        p1[r] = EXP2F(St1[r]);
      }
      half8 pf = cvt8v(p0, p1);          // B[k=quad*8+j][q=l16] directly
      Ot[0][g] = mfma16(vc0, pf, Ot[0][g]);
      Ot[1][g] = mfma16(vc1, pf, Ot[1][g]);
      Lacc[g]  = mfma16(ones, pf, Lacc[g]);
    }
    kc0 = kn0; kc1 = kn1; vc0 = vn0; vc1 = vn1;
  }

  // normalize in-register (lsum for q=g*16+l16 sits on lane l16, reg 0),
  // pack fp16, store into LDS ctx tile: ctxL[q][wid*32 + dk]
  unsigned int* cL = (unsigned int*)ctxL;
#pragma unroll
  for (int g = 0; g < 2; ++g) {
    float linv = 1.0f / __shfl(Lacc[g][0], l16);
    int row = g * 16 + l16;
#pragma unroll
    for (int d = 0; d < 2; ++d) {
      int base = row * 140 + wid * 16 + d * 8 + quad * 2;
      cL[base]     = pk2(Ot[d][g][0] * linv, Ot[d][g][1] * linv);
      cL[base + 1] = pk2(Ot[d][g][2] * linv, Ot[d][g][3] * linv);
    }
  }
  __syncthreads();           // ctx tile complete AND Wo stage-0 resident

  // ---- oproj phase: out[32 x 256] = ctx @ Wo^T + bo, Wo streamed 4x64 cols
  int widm = wid >> 2, widn = wid & 3;   // 2 row-groups x 4 col-quarters
  int tokbase = (b * 8 + p) * 1024 + qrow0;
  half8 a16[8];
#pragma unroll
  for (int ks = 0; ks < 8; ++ks)
    a16[ks] = *(const half8*)(ctxL + (widm * 16 + l16) * 280 + ks * 32 + quad * 8);

  for (int s = 0; s < 4; ++s) {
    if (s) __syncthreads();              // Wo stage s resident
    f32x4 acc = {};
#pragma unroll
    for (int ks = 0; ks < 8; ++ks) {
      half8 bf = *(const half8*)(Wb + ((size_t)(widn * 8 + ks)) * 512 + lane * 8);
      acc = mfma16(a16[ks], bf, acc);
    }
    __syncthreads();                     // all waves done with Wb
    if (s < 3) {
#pragma unroll
      for (int it = 0; it < 4; ++it)
        g2lds16(WF3 + (size_t)(s + 1) * 16384 + it * 4096 + wid * 512 + lane * 8,
                Wb + it * 4096 + wid * 512);
    }
    int o = s * 64 + widn * 16 + l16;
    float bval = bo[o];
#pragma unroll
    for (int r = 0; r < 4; ++r)
      out[(size_t)(tokbase + widm * 16 + quad * 4 + r) * 256 + o] = acc[r] + bval;
  }
}

extern "C" void kernel_launch(void* const* d_in, const int* in_sizes, int n_in,
                              void* d_out, int out_size, void* d_ws, size_t ws_size,
                              hipStream_t stream)
{
  const float* q  = (const float*)d_in[0];
  const float* k  = (const float*)d_in[1];
  const float* v  = (const float*)d_in[2];
  const float* Wq = (const float*)d_in[3];
  const float* bq = (const float*)d_in[4];
  const float* Wk = (const float*)d_in[5];
  const float* bk = (const float*)d_in[6];
  const float* Wv = (const float*)d_in[7];
  const float* bv = (const float*)d_in[8];
  const float* Wo = (const float*)d_in[9];
  const float* bo = (const float*)d_in[10];
  _Float16* ws = (_Float16*)d_ws;
  float* out = (float*)d_out;

  prep_kernel<<<128, 256, 0, stream>>>(Wq, Wk, Wv, Wo, ws);
  proj_kernel<<<dim3(256, 3), 256, 0, stream>>>(q, k, v, bq, bk, bv, ws);
  attno_kernel<<<512, 512, 0, stream>>>(ws, bo, out);   // 16 (b,p) x 32 qc
}

// Round 11
// 151.056 us; speedup vs baseline: 1.1135x; 1.1135x over previous
//
#include <hip/hip_runtime.h>

// RoutingAttention gfx950 — R20.
// R19 lesson: block-TLP bought with per-wave ILP regresses (57us, MfmaUtil
// 15%). R20: split-K fusion — 64-row tiles (4 q-chains/wave, R18 ILP) but
// 16 waves/block = (head, K-half): 4 waves/SIMD at CONSTANT chain count.
// 2-way fp16 partial merge in LDS (cut-down of R10's proven 4-way merge),
// then 16-wave streamed-Wo oproj. LDS 103KB, 1 block/CU, VGPR capped 128.
// proj (one-launch, top-level mode split) and prep unchanged from R18.
// B=2 P=8 S=1024 C=256 NH=8 DK=32; T=16384.

typedef _Float16 half8 __attribute__((ext_vector_type(8)));
typedef _Float16 half4 __attribute__((ext_vector_type(4)));
typedef float f32x4 __attribute__((ext_vector_type(4)));

#if __has_builtin(__builtin_amdgcn_exp2f)
#define EXP2F(x) __builtin_amdgcn_exp2f(x)
#else
#define EXP2F(x) exp2f(x)
#endif

__device__ __forceinline__ f32x4 mfma16(half8 a, half8 b, f32x4 c) {
  return __builtin_amdgcn_mfma_f32_16x16x32_f16(a, b, c, 0, 0, 0);
}

__device__ __forceinline__ int pk2(float a, float b) {
  auto h = __builtin_amdgcn_cvt_pkrtz(a, b);
  return __builtin_bit_cast(int, h);
}

__device__ __forceinline__ half8 cvt8(float4 f0, float4 f1) {
  union { int i[4]; half8 h; } u;
  u.i[0] = pk2(f0.x, f0.y); u.i[1] = pk2(f0.z, f0.w);
  u.i[2] = pk2(f1.x, f1.y); u.i[3] = pk2(f1.z, f1.w);
  return u.h;
}

__device__ __forceinline__ half8 cvt8v(f32x4 f0, f32x4 f1) {
  union { int i[4]; half8 h; } u;
  u.i[0] = pk2(f0[0], f0[1]); u.i[1] = pk2(f0[2], f0[3]);
  u.i[2] = pk2(f1[0], f1[1]); u.i[3] = pk2(f1[2], f1[3]);
  return u.h;
}

// async global->LDS, 16B per lane; lds dest = wave-uniform base + lane*16
__device__ __forceinline__ void g2lds16(const _Float16* g, _Float16* l) {
  __builtin_amdgcn_global_load_lds(
      (const __attribute__((address_space(1))) void*)g,
      (__attribute__((address_space(3))) void*)l, 16, 0, 0);
}

// ws layout (halves)
static constexpr size_t QH_OFF  = 0;          // (win,s,dk), q scaled log2(e)/sqrt(32)
static constexpr size_t KH_OFF  = 4194304;    // (win,s,dk)
static constexpr size_t VT_OFF  = 8388608;    // (win,dk,s)
static constexpr size_t WF_OFF  = 16777216;   // 4 mats frag-contiguous fp16

// ---------------- W prep: fp32 -> fp16 frag-contiguous ----------------
__global__ __launch_bounds__(256) void prep_kernel(
    const float* __restrict__ wq, const float* __restrict__ wk,
    const float* __restrict__ wv, const float* __restrict__ wo,
    _Float16* __restrict__ ws)
{
  int u = blockIdx.x * 256 + threadIdx.x;          // 0..32767
  int lane = u & 63, ks = (u >> 6) & 7, nt = (u >> 9) & 15, mat = u >> 13;
  const float* W = (mat == 0) ? wq : (mat == 1) ? wk : (mat == 2) ? wv : wo;
  const float* p = W + (size_t)(nt * 16 + (lane & 15)) * 256 + ks * 32 + (lane >> 4) * 8;
  half8 h = cvt8(*(const float4*)p, *(const float4*)(p + 4));
  *(half8*)(ws + WF_OFF + (size_t)u * 8) = h;
}

// ---------------- Q/K/V projection: ONE launch, top-level mode split --------
// mode = blockIdx.y: 0=q, 1=k (row-layout epilogue), 2=v (V^T epilogue).
// Each branch is the verbatim R15-proven single-epilogue pipelined body.
__global__ __launch_bounds__(256, 3) void proj_kernel(
    const float* __restrict__ xq, const float* __restrict__ xk,
    const float* __restrict__ xv,
    const float* __restrict__ bq, const float* __restrict__ bk,
    const float* __restrict__ bv,
    _Float16* __restrict__ ws)
{
  __shared__ __align__(16) _Float16 Wb[16384 + 4608];  // 32KB W stage + 9KB Lt

  int mode = blockIdx.y;
  if (mode < 2) {
    // ================= Q/K body (verbatim R15 qkproj) =================
    _Float16* Lt = Wb + 16384;
    const float* X  = mode ? xk : xq;
    const float* bias = mode ? bk : bq;
    const _Float16* WFm = ws + WF_OFF + (size_t)mode * 65536;
    _Float16* outp = ws + (mode ? KH_OFF : QH_OFF);
    const float scale = mode ? 1.0f : 0.2550348654f;  // log2(e)/sqrt(32)

    int tid = threadIdx.x, lane = tid & 63, wid = tid >> 6;
    int l16 = lane & 15, quad = lane >> 4;
    int m0 = blockIdx.x * 64;
    int b = m0 >> 13, p = (m0 >> 10) & 7, s0 = m0 & 1023;

#pragma unroll
    for (int it = 0; it < 8; ++it)
      g2lds16(WFm + it * 2048 + wid * 512 + lane * 8, Wb + it * 2048 + wid * 512);

    const float* r0 = X + (size_t)(m0 + wid * 16 + l16) * 256 + quad * 8;
    float4 xa[8][2];
#pragma unroll
    for (int ks = 0; ks < 8; ++ks) {
      xa[ks][0] = *(const float4*)(r0 + ks * 32);
      xa[ks][1] = *(const float4*)(r0 + ks * 32 + 4);
    }
    half8 a16[8];
#pragma unroll
    for (int ks = 0; ks < 8; ++ks) a16[ks] = cvt8(xa[ks][0], xa[ks][1]);

    for (int s = 0; s < 4; ++s) {
      __syncthreads();                       // W stage s resident
      f32x4 acc[4] = {};
#pragma unroll
      for (int ks = 0; ks < 8; ++ks)
#pragma unroll
        for (int t = 0; t < 4; ++t) {
          half8 bf = *(const half8*)(Wb + ((size_t)(t * 8 + ks)) * 512 + lane * 8);
          acc[t] = mfma16(a16[ks], bf, acc[t]);
        }
      // Q/K: Lt[row][col], stride 72 halves = 144B (16B-aligned rows)
#pragma unroll
      for (int t = 0; t < 4; ++t) {
        float bval = bias[s * 64 + t * 16 + l16];
#pragma unroll
        for (int r = 0; r < 4; ++r)
          Lt[(wid * 16 + quad * 4 + r) * 72 + t * 16 + l16] =
              (_Float16)((acc[t][r] + bval) * scale);
      }
      __syncthreads();                       // Lt ready AND all waves done w/ Wb
      if (s < 3) {
#pragma unroll
        for (int it = 0; it < 8; ++it)
          g2lds16(WFm + (size_t)(s + 1) * 16384 + it * 2048 + wid * 512 + lane * 8,
                  Wb + it * 2048 + wid * 512);
      }
      // stage s covers out-cols s*64..s*64+63 = heads 2s, 2s+1
#pragma unroll
      for (int j = 0; j < 2; ++j) {
        int chunk = j * 256 + tid;
        int row = chunk >> 3, c8 = chunk & 7;
        half8 v = *(const half8*)(Lt + row * 72 + c8 * 8);
        int h = s * 2 + (c8 >> 2);
        size_t wbase = (size_t)((b * 8 + h) * 8 + p) * 32768;
        *(half8*)(outp + wbase + (size_t)(s0 + row) * 32 + (c8 & 3) * 8) = v;
      }
    }
  } else {
    // ================= V body (verbatim R15 vproj) =================
    _Float16* Lt = Wb + 16384;
    const _Float16* WFm = ws + WF_OFF + (size_t)2 * 65536;
    _Float16* outp = ws + VT_OFF;

    int tid = threadIdx.x, lane = tid & 63, wid = tid >> 6;
    int l16 = lane & 15, quad = lane >> 4;
    int m0 = blockIdx.x * 64;
    int b = m0 >> 13, p = (m0 >> 10) & 7, s0 = m0 & 1023;

#pragma unroll
    for (int it = 0; it < 8; ++it)
      g2lds16(WFm + it * 2048 + wid * 512 + lane * 8, Wb + it * 2048 + wid * 512);

    const float* r0 = xv + (size_t)(m0 + wid * 16 + l16) * 256 + quad * 8;
    float4 xa[8][2];
#pragma unroll
    for (int ks = 0; ks < 8; ++ks) {
      xa[ks][0] = *(const float4*)(r0 + ks * 32);
      xa[ks][1] = *(const float4*)(r0 + ks * 32 + 4);
    }
    half8 a16[8];
#pragma unroll
    for (int ks = 0; ks < 8; ++ks) a16[ks] = cvt8(xa[ks][0], xa[ks][1]);

    for (int s = 0; s < 4; ++s) {
      __syncthreads();                       // W stage s resident
      f32x4 acc[4] = {};
#pragma unroll
      for (int ks = 0; ks < 8; ++ks)
#pragma unroll
        for (int t = 0; t < 4; ++t) {
          half8 bf = *(const half8*)(Wb + ((size_t)(t * 8 + ks)) * 512 + lane * 8);
          acc[t] = mfma16(a16[ks], bf, acc[t]);
        }
      // V^T: Lt[col][row], stride 72 (rows 16B-aligned)
#pragma unroll
      for (int t = 0; t < 4; ++t) {
        float bval = bv[s * 64 + t * 16 + l16];
        half4 h4;
#pragma unroll
        for (int r = 0; r < 4; ++r) h4[r] = (_Float16)(acc[t][r] + bval);
        *(half4*)(Lt + (t * 16 + l16) * 72 + wid * 16 + quad * 4) = h4;
      }
      __syncthreads();                       // Lt ready AND all waves done w/ Wb
      if (s < 3) {
#pragma unroll
        for (int it = 0; it < 8; ++it)
          g2lds16(WFm + (size_t)(s + 1) * 16384 + it * 2048 + wid * 512 + lane * 8,
                  Wb + it * 2048 + wid * 512);
      }
#pragma unroll
      for (int j = 0; j < 2; ++j) {
        int chunk = j * 256 + tid;
        int col = chunk >> 3, r8 = chunk & 7;
        half8 v = *(const half8*)(Lt + col * 72 + r8 * 8);
        int o = s * 64 + col;
        int h = o >> 5, dki = o & 31;
        size_t wbase = (size_t)((b * 8 + h) * 8 + p) * 32768;
        *(half8*)(outp + wbase + (size_t)dki * 1024 + s0 + r8 * 8) = v;
      }
    }
  }
}

// ---------------- fused attention + output projection (split-K, 16 waves) ---
// Block (b,p,qc): 64 tokens, 16 waves = (head 0..7) x (K-half 0..1), each
// wave 4 q-chains over 512 K-rows (R18 ILP at 2x TLP: 4 waves/SIMD).
// Upper waves (kh=1) publish fp16-packed Ot + f32 lsum to LDS; lower waves
// merge + normalize + write ctxL [64][280]; 16-wave 4-stage streamed-Wo
// oproj (4 row-groups x 4 col-tiles) writes fp32 out.
__global__ __launch_bounds__(1024, 4) void attno_kernel(
    const _Float16* __restrict__ ws, const float* __restrict__ bo,
    float* __restrict__ out)
{
  __shared__ __align__(16) _Float16 smem[52736];  // 103KB
  _Float16* Wb = smem;                            // [16384] Wo stage
  _Float16* ctxL = smem + 16384;                  // [64][280]
  unsigned int* OfU = (unsigned int*)(smem + 34304);  // [8][64][17] u32
  float* Ls = (float*)(smem + 51712);             // [8][64]

  int tid = threadIdx.x, lane = tid & 63, wid = tid >> 6;   // 16 waves
  int l16 = lane & 15, quad = lane >> 4;
  int head = wid & 7, kh = wid >> 3;              // head, K-half
  int w = blockIdx.x & 15, qc = blockIdx.x >> 4;  // XCD-clustered (16 apart)
  int b = w >> 3, p = w & 7;
  int qrow0 = qc * 64;
  size_t hb = (size_t)((b * 8 + head) * 8 + p) * 32768;
  const _Float16* qhw = ws + QH_OFF + hb;
  const _Float16* khw = ws + KH_OFF + hb;
  const _Float16* vtw = ws + VT_OFF + hb;
  const _Float16* WF3 = ws + WF_OFF + (size_t)3 * 65536;

  // stage-0 Wo -> LDS (16 waves x 1024 halves)
#pragma unroll
  for (int it = 0; it < 2; ++it)
    g2lds16(WF3 + it * 8192 + wid * 512 + lane * 8, Wb + it * 8192 + wid * 512);

  half8 qf[4];
#pragma unroll
  for (int g = 0; g < 4; ++g)
    qf[g] = *(const half8*)(qhw + (size_t)(qrow0 + g * 16 + l16) * 32 + quad * 8);

  // ones A-frag: row m=0 only -> lsum lands in C row 0 (quad==0, reg 0)
  half8 ones = {};
  if (l16 == 0) {
#pragma unroll
    for (int j = 0; j < 8; ++j) ones[j] = (_Float16)1.0f;
  }

  // permuted K row indices: A-row m holds k = (m>>2)*8 + (m&3) (+4 for kc1)
  int kp0 = ((l16 >> 2) << 3) + (l16 & 3);
  int kp1 = kp0 + 4;

  f32x4 Ot[2][4] = {};      // [dk-tile][q-group] O^T partials
  f32x4 Lacc[4] = {};       // lsum via ones-row MFMA
  int kbase = kh * 512;

  half8 kc0 = *(const half8*)(khw + (size_t)(kbase + kp0) * 32 + quad * 8);
  half8 kc1 = *(const half8*)(khw + (size_t)(kbase + kp1) * 32 + quad * 8);
  half8 vc0 = *(const half8*)(vtw + (size_t)l16 * 1024 + kbase + quad * 8);
  half8 vc1 = *(const half8*)(vtw + (size_t)(16 + l16) * 1024 + kbase + quad * 8);

  for (int kk = 0; kk < 16; ++kk) {
    int kn = kbase + (((kk + 1) & 15) << 5);
    half8 kn0 = *(const half8*)(khw + (size_t)(kn + kp0) * 32 + quad * 8);
    half8 kn1 = *(const half8*)(khw + (size_t)(kn + kp1) * 32 + quad * 8);
    half8 vn0 = *(const half8*)(vtw + (size_t)l16 * 1024 + kn + quad * 8);
    half8 vn1 = *(const half8*)(vtw + (size_t)(16 + l16) * 1024 + kn + quad * 8);

    f32x4 z = {0.f, 0.f, 0.f, 0.f};
#pragma unroll
    for (int g = 0; g < 4; ++g) {
      f32x4 St0 = mfma16(kc0, qf[g], z);
      f32x4 St1 = mfma16(kc1, qf[g], z);
      f32x4 p0, p1;
#pragma unroll
      for (int r = 0; r < 4; ++r) {
        p0[r] = EXP2F(St0[r]);
        p1[r] = EXP2F(St1[r]);
      }
      half8 pf = cvt8v(p0, p1);          // B[k=quad*8+j][q=l16] directly
      Ot[0][g] = mfma16(vc0, pf, Ot[0][g]);
      Ot[1][g] = mfma16(vc1, pf, Ot[1][g]);
      Lacc[g]  = mfma16(ones, pf, Lacc[g]);
    }
    kc0 = kn0; kc1 = kn1; vc0 = vn0; vc1 = vn1;
  }

  // ---- upper K-half publishes partials (fp16 Ot pairs + f32 lsum) ----
  if (kh) {
    if (quad == 0) {
#pragma unroll
      for (int g = 0; g < 4; ++g) Ls[head * 64 + g * 16 + l16] = Lacc[g][0];
    }
#pragma unroll
    for (int d = 0; d < 2; ++d)
#pragma unroll
      for (int g = 0; g < 4; ++g) {
        int base = head * 1088 + (g * 16 + l16) * 17 + d * 8 + quad * 2;
        OfU[base]     = pk2(Ot[d][g][0], Ot[d][g][1]);
        OfU[base + 1] = pk2(Ot[d][g][2], Ot[d][g][3]);
      }
  }
  __syncthreads();           // partials ready AND Wo stage-0 resident

  // ---- lower K-half merges, normalizes, writes ctx tile ----
  if (!kh) {
    unsigned int* cL = (unsigned int*)ctxL;
#pragma unroll
    for (int g = 0; g < 4; ++g) {
      int row = g * 16 + l16;
      float lt = __shfl(Lacc[g][0], l16) + Ls[head * 64 + row];
      float linv = 1.0f / lt;
#pragma unroll
      for (int d = 0; d < 2; ++d) {
        int ubase = head * 1088 + row * 17 + d * 8 + quad * 2;
        union { unsigned int x; _Float16 h2[2]; } u0, u1;
        u0.x = OfU[ubase]; u1.x = OfU[ubase + 1];
        int base = row * 140 + head * 16 + d * 8 + quad * 2;
        cL[base]     = pk2((Ot[d][g][0] + (float)u0.h2[0]) * linv,
                           (Ot[d][g][1] + (float)u0.h2[1]) * linv);
        cL[base + 1] = pk2((Ot[d][g][2] + (float)u1.h2[0]) * linv,
                           (Ot[d][g][3] + (float)u1.h2[1]) * linv);
      }
    }
  }
  __syncthreads();           // ctx tile complete

  // ---- oproj phase: out[64 x 256] = ctx @ Wo^T + bo, Wo streamed 4x64 cols
  int widm = wid >> 2, widn = wid & 3;   // 4 row-groups x 4 col-tiles
  int tokbase = (b * 8 + p) * 1024 + qrow0;
  half8 a16[8];
#pragma unroll
  for (int ks = 0; ks < 8; ++ks)
    a16[ks] = *(const half8*)(ctxL + (widm * 16 + l16) * 280 + ks * 32 + quad * 8);

  for (int s = 0; s < 4; ++s) {
    if (s) __syncthreads();              // Wo stage s resident
    f32x4 acc = {};
#pragma unroll
    for (int ks = 0; ks < 8; ++ks) {
      half8 bf = *(const half8*)(Wb + ((size_t)(widn * 8 + ks)) * 512 + lane * 8);
      acc = mfma16(a16[ks], bf, acc);
    }
    __syncthreads();                     // all waves done with Wb
    if (s < 3) {
#pragma unroll
      for (int it = 0; it < 2; ++it)
        g2lds16(WF3 + (size_t)(s + 1) * 16384 + it * 8192 + wid * 512 + lane * 8,
                Wb + it * 8192 + wid * 512);
    }
    int o = s * 64 + widn * 16 + l16;
    float bval = bo[o];
#pragma unroll
    for (int r = 0; r < 4; ++r)
      out[(size_t)(tokbase + widm * 16 + quad * 4 + r) * 256 + o] = acc[r] + bval;
  }
}

extern "C" void kernel_launch(void* const* d_in, const int* in_sizes, int n_in,
                              void* d_out, int out_size, void* d_ws, size_t ws_size,
                              hipStream_t stream)
{
  const float* q  = (const float*)d_in[0];
  const float* k  = (const float*)d_in[1];
  const float* v  = (const float*)d_in[2];
  const float* Wq = (const float*)d_in[3];
  const float* bq = (const float*)d_in[4];
  const float* Wk = (const float*)d_in[5];
  const float* bk = (const float*)d_in[6];
  const float* Wv = (const float*)d_in[7];
  const float* bv = (const float*)d_in[8];
  const float* Wo = (const float*)d_in[9];
  const float* bo = (const float*)d_in[10];
  _Float16* ws = (_Float16*)d_ws;
  float* out = (float*)d_out;

  prep_kernel<<<128, 256, 0, stream>>>(Wq, Wk, Wv, Wo, ws);
  proj_kernel<<<dim3(256, 3), 256, 0, stream>>>(q, k, v, bq, bk, bv, ws);
  attno_kernel<<<256, 1024, 0, stream>>>(ws, bo, out);   // 16 (b,p) x 16 qc
}

// Round 12
// 150.224 us; speedup vs baseline: 1.1197x; 1.0055x over previous
//
#include <hip/hip_runtime.h>

// RoutingAttention gfx950 — R21 (= R18 + depth-2 K/V prefetch in attno).
// R19 (half ILP) +18us, R20 (2x TLP) neutral => attn interior pinned ~39us
// by in-wave load latency that extra waves don't cover (all waves stall at
// the same vmcnt). Fix: register-level 2-deep pipeline — loop unrolled 2x,
// loads for kk+2/kk+3 issued BEFORE computing kk/kk+1 (2 compute bodies of
// latency coverage). Everything else byte-identical to R18 (149.9us).
// B=2 P=8 S=1024 C=256 NH=8 DK=32; T=16384.

typedef _Float16 half8 __attribute__((ext_vector_type(8)));
typedef _Float16 half4 __attribute__((ext_vector_type(4)));
typedef float f32x4 __attribute__((ext_vector_type(4)));

#if __has_builtin(__builtin_amdgcn_exp2f)
#define EXP2F(x) __builtin_amdgcn_exp2f(x)
#else
#define EXP2F(x) exp2f(x)
#endif

__device__ __forceinline__ f32x4 mfma16(half8 a, half8 b, f32x4 c) {
  return __builtin_amdgcn_mfma_f32_16x16x32_f16(a, b, c, 0, 0, 0);
}

__device__ __forceinline__ int pk2(float a, float b) {
  auto h = __builtin_amdgcn_cvt_pkrtz(a, b);
  return __builtin_bit_cast(int, h);
}

__device__ __forceinline__ half8 cvt8(float4 f0, float4 f1) {
  union { int i[4]; half8 h; } u;
  u.i[0] = pk2(f0.x, f0.y); u.i[1] = pk2(f0.z, f0.w);
  u.i[2] = pk2(f1.x, f1.y); u.i[3] = pk2(f1.z, f1.w);
  return u.h;
}

__device__ __forceinline__ half8 cvt8v(f32x4 f0, f32x4 f1) {
  union { int i[4]; half8 h; } u;
  u.i[0] = pk2(f0[0], f0[1]); u.i[1] = pk2(f0[2], f0[3]);
  u.i[2] = pk2(f1[0], f1[1]); u.i[3] = pk2(f1[2], f1[3]);
  return u.h;
}

// async global->LDS, 16B per lane; lds dest = wave-uniform base + lane*16
__device__ __forceinline__ void g2lds16(const _Float16* g, _Float16* l) {
  __builtin_amdgcn_global_load_lds(
      (const __attribute__((address_space(1))) void*)g,
      (__attribute__((address_space(3))) void*)l, 16, 0, 0);
}

// ws layout (halves)
static constexpr size_t QH_OFF  = 0;          // (win,s,dk), q scaled log2(e)/sqrt(32)
static constexpr size_t KH_OFF  = 4194304;    // (win,s,dk)
static constexpr size_t VT_OFF  = 8388608;    // (win,dk,s)
static constexpr size_t WF_OFF  = 16777216;   // 4 mats frag-contiguous fp16

// ---------------- W prep: fp32 -> fp16 frag-contiguous ----------------
__global__ __launch_bounds__(256) void prep_kernel(
    const float* __restrict__ wq, const float* __restrict__ wk,
    const float* __restrict__ wv, const float* __restrict__ wo,
    _Float16* __restrict__ ws)
{
  int u = blockIdx.x * 256 + threadIdx.x;          // 0..32767
  int lane = u & 63, ks = (u >> 6) & 7, nt = (u >> 9) & 15, mat = u >> 13;
  const float* W = (mat == 0) ? wq : (mat == 1) ? wk : (mat == 2) ? wv : wo;
  const float* p = W + (size_t)(nt * 16 + (lane & 15)) * 256 + ks * 32 + (lane >> 4) * 8;
  half8 h = cvt8(*(const float4*)p, *(const float4*)(p + 4));
  *(half8*)(ws + WF_OFF + (size_t)u * 8) = h;
}

// ---------------- Q/K/V projection: ONE launch, top-level mode split --------
// mode = blockIdx.y: 0=q, 1=k (row-layout epilogue), 2=v (V^T epilogue).
// Each branch is the verbatim R15-proven single-epilogue pipelined body.
__global__ __launch_bounds__(256, 3) void proj_kernel(
    const float* __restrict__ xq, const float* __restrict__ xk,
    const float* __restrict__ xv,
    const float* __restrict__ bq, const float* __restrict__ bk,
    const float* __restrict__ bv,
    _Float16* __restrict__ ws)
{
  __shared__ __align__(16) _Float16 Wb[16384 + 4608];  // 32KB W stage + 9KB Lt

  int mode = blockIdx.y;
  if (mode < 2) {
    // ================= Q/K body (verbatim R15 qkproj) =================
    _Float16* Lt = Wb + 16384;
    const float* X  = mode ? xk : xq;
    const float* bias = mode ? bk : bq;
    const _Float16* WFm = ws + WF_OFF + (size_t)mode * 65536;
    _Float16* outp = ws + (mode ? KH_OFF : QH_OFF);
    const float scale = mode ? 1.0f : 0.2550348654f;  // log2(e)/sqrt(32)

    int tid = threadIdx.x, lane = tid & 63, wid = tid >> 6;
    int l16 = lane & 15, quad = lane >> 4;
    int m0 = blockIdx.x * 64;
    int b = m0 >> 13, p = (m0 >> 10) & 7, s0 = m0 & 1023;

#pragma unroll
    for (int it = 0; it < 8; ++it)
      g2lds16(WFm + it * 2048 + wid * 512 + lane * 8, Wb + it * 2048 + wid * 512);

    const float* r0 = X + (size_t)(m0 + wid * 16 + l16) * 256 + quad * 8;
    float4 xa[8][2];
#pragma unroll
    for (int ks = 0; ks < 8; ++ks) {
      xa[ks][0] = *(const float4*)(r0 + ks * 32);
      xa[ks][1] = *(const float4*)(r0 + ks * 32 + 4);
    }
    half8 a16[8];
#pragma unroll
    for (int ks = 0; ks < 8; ++ks) a16[ks] = cvt8(xa[ks][0], xa[ks][1]);

    for (int s = 0; s < 4; ++s) {
      __syncthreads();                       // W stage s resident
      f32x4 acc[4] = {};
#pragma unroll
      for (int ks = 0; ks < 8; ++ks)
#pragma unroll
        for (int t = 0; t < 4; ++t) {
          half8 bf = *(const half8*)(Wb + ((size_t)(t * 8 + ks)) * 512 + lane * 8);
          acc[t] = mfma16(a16[ks], bf, acc[t]);
        }
      // Q/K: Lt[row][col], stride 72 halves = 144B (16B-aligned rows)
#pragma unroll
      for (int t = 0; t < 4; ++t) {
        float bval = bias[s * 64 + t * 16 + l16];
#pragma unroll
        for (int r = 0; r < 4; ++r)
          Lt[(wid * 16 + quad * 4 + r) * 72 + t * 16 + l16] =
              (_Float16)((acc[t][r] + bval) * scale);
      }
      __syncthreads();                       // Lt ready AND all waves done w/ Wb
      if (s < 3) {
#pragma unroll
        for (int it = 0; it < 8; ++it)
          g2lds16(WFm + (size_t)(s + 1) * 16384 + it * 2048 + wid * 512 + lane * 8,
                  Wb + it * 2048 + wid * 512);
      }
      // stage s covers out-cols s*64..s*64+63 = heads 2s, 2s+1
#pragma unroll
      for (int j = 0; j < 2; ++j) {
        int chunk = j * 256 + tid;
        int row = chunk >> 3, c8 = chunk & 7;
        half8 v = *(const half8*)(Lt + row * 72 + c8 * 8);
        int h = s * 2 + (c8 >> 2);
        size_t wbase = (size_t)((b * 8 + h) * 8 + p) * 32768;
        *(half8*)(outp + wbase + (size_t)(s0 + row) * 32 + (c8 & 3) * 8) = v;
      }
    }
  } else {
    // ================= V body (verbatim R15 vproj) =================
    _Float16* Lt = Wb + 16384;
    const _Float16* WFm = ws + WF_OFF + (size_t)2 * 65536;
    _Float16* outp = ws + VT_OFF;

    int tid = threadIdx.x, lane = tid & 63, wid = tid >> 6;
    int l16 = lane & 15, quad = lane >> 4;
    int m0 = blockIdx.x * 64;
    int b = m0 >> 13, p = (m0 >> 10) & 7, s0 = m0 & 1023;

#pragma unroll
    for (int it = 0; it < 8; ++it)
      g2lds16(WFm + it * 2048 + wid * 512 + lane * 8, Wb + it * 2048 + wid * 512);

    const float* r0 = xv + (size_t)(m0 + wid * 16 + l16) * 256 + quad * 8;
    float4 xa[8][2];
#pragma unroll
    for (int ks = 0; ks < 8; ++ks) {
      xa[ks][0] = *(const float4*)(r0 + ks * 32);
      xa[ks][1] = *(const float4*)(r0 + ks * 32 + 4);
    }
    half8 a16[8];
#pragma unroll
    for (int ks = 0; ks < 8; ++ks) a16[ks] = cvt8(xa[ks][0], xa[ks][1]);

    for (int s = 0; s < 4; ++s) {
      __syncthreads();                       // W stage s resident
      f32x4 acc[4] = {};
#pragma unroll
      for (int ks = 0; ks < 8; ++ks)
#pragma unroll
        for (int t = 0; t < 4; ++t) {
          half8 bf = *(const half8*)(Wb + ((size_t)(t * 8 + ks)) * 512 + lane * 8);
          acc[t] = mfma16(a16[ks], bf, acc[t]);
        }
      // V^T: Lt[col][row], stride 72 (rows 16B-aligned)
#pragma unroll
      for (int t = 0; t < 4; ++t) {
        float bval = bv[s * 64 + t * 16 + l16];
        half4 h4;
#pragma unroll
        for (int r = 0; r < 4; ++r) h4[r] = (_Float16)(acc[t][r] + bval);
        *(half4*)(Lt + (t * 16 + l16) * 72 + wid * 16 + quad * 4) = h4;
      }
      __syncthreads();                       // Lt ready AND all waves done w/ Wb
      if (s < 3) {
#pragma unroll
        for (int it = 0; it < 8; ++it)
          g2lds16(WFm + (size_t)(s + 1) * 16384 + it * 2048 + wid * 512 + lane * 8,
                  Wb + it * 2048 + wid * 512);
      }
#pragma unroll
      for (int j = 0; j < 2; ++j) {
        int chunk = j * 256 + tid;
        int col = chunk >> 3, r8 = chunk & 7;
        half8 v = *(const half8*)(Lt + col * 72 + r8 * 8);
        int o = s * 64 + col;
        int h = o >> 5, dki = o & 31;
        size_t wbase = (size_t)((b * 8 + h) * 8 + p) * 32768;
        *(half8*)(outp + wbase + (size_t)dki * 1024 + s0 + r8 * 8) = v;
      }
    }
  }
}

// ---------------- fused attention + output projection -----------------------
// Block (b,p,qc): 64 tokens, 8 waves = 8 heads, full-K per wave.
// attn K-loop: 2x unrolled with depth-2 register prefetch (loads for kk+2
// issued before computing kk). Everything else as R18.
__global__ __launch_bounds__(512) void attno_kernel(
    const _Float16* __restrict__ ws, const float* __restrict__ bo,
    float* __restrict__ out)
{
  __shared__ __align__(16) _Float16 smem[16384 + 17920];  // Wo 32KB + ctx 35KB
  _Float16* Wb = smem;
  _Float16* ctxL = smem + 16384;                 // [64][280] halves

  int tid = threadIdx.x, lane = tid & 63, wid = tid >> 6;   // wid = head
  int l16 = lane & 15, quad = lane >> 4;
  int w = blockIdx.x & 15, qc = blockIdx.x >> 4; // XCD-clustered (16 apart)
  int b = w >> 3, p = w & 7;
  int qrow0 = qc * 64;
  size_t hb = (size_t)((b * 8 + wid) * 8 + p) * 32768;
  const _Float16* qhw = ws + QH_OFF + hb;
  const _Float16* khw = ws + KH_OFF + hb;
  const _Float16* vtw = ws + VT_OFF + hb;
  const _Float16* WF3 = ws + WF_OFF + (size_t)3 * 65536;

  // stage-0 Wo -> LDS, issued first (resident long before oproj phase)
#pragma unroll
  for (int it = 0; it < 4; ++it)
    g2lds16(WF3 + it * 4096 + wid * 512 + lane * 8, Wb + it * 4096 + wid * 512);

  half8 qf[4];
#pragma unroll
  for (int g = 0; g < 4; ++g)
    qf[g] = *(const half8*)(qhw + (size_t)(qrow0 + g * 16 + l16) * 32 + quad * 8);

  // ones A-frag: row m=0 only -> lsum lands in C row 0 (quad==0, reg 0)
  half8 ones = {};
  if (l16 == 0) {
#pragma unroll
    for (int j = 0; j < 8; ++j) ones[j] = (_Float16)1.0f;
  }

  // permuted K row indices: A-row m holds k = (m>>2)*8 + (m&3) (+4 for kc1)
  int kp0 = ((l16 >> 2) << 3) + (l16 & 3);
  int kp1 = kp0 + 4;

  f32x4 Ot[2][4] = {};      // [dk-tile][q-group] O^T partials
  f32x4 Lacc[4] = {};       // lsum via ones-row MFMA

  auto LK0 = [&](int kb) {
    return *(const half8*)(khw + (size_t)(kb + kp0) * 32 + quad * 8);
  };
  auto LK1 = [&](int kb) {
    return *(const half8*)(khw + (size_t)(kb + kp1) * 32 + quad * 8);
  };
  auto LV0 = [&](int kb) {
    return *(const half8*)(vtw + (size_t)l16 * 1024 + kb + quad * 8);
  };
  auto LV1 = [&](int kb) {
    return *(const half8*)(vtw + (size_t)(16 + l16) * 1024 + kb + quad * 8);
  };
  auto STEP = [&](half8 k0, half8 k1, half8 v0, half8 v1) {
    f32x4 z = {0.f, 0.f, 0.f, 0.f};
#pragma unroll
    for (int g = 0; g < 4; ++g) {
      f32x4 St0 = mfma16(k0, qf[g], z);
      f32x4 St1 = mfma16(k1, qf[g], z);
      f32x4 p0, p1;
#pragma unroll
      for (int r = 0; r < 4; ++r) {
        p0[r] = EXP2F(St0[r]);
        p1[r] = EXP2F(St1[r]);
      }
      half8 pf = cvt8v(p0, p1);          // B[k=quad*8+j][q=l16] directly
      Ot[0][g] = mfma16(v0, pf, Ot[0][g]);
      Ot[1][g] = mfma16(v1, pf, Ot[1][g]);
      Lacc[g]  = mfma16(ones, pf, Lacc[g]);
    }
  };

  // depth-2 register pipeline: slots a (kk), b (kk+1); prefetch kk+2, kk+3
  half8 ak0 = LK0(0),  ak1 = LK1(0),  av0 = LV0(0),  av1 = LV1(0);
  half8 bk0 = LK0(32), bk1 = LK1(32), bv0 = LV0(32), bv1 = LV1(32);

  for (int kk = 0; kk < 32; kk += 2) {
    int kn2 = ((kk + 2) & 31) << 5;
    half8 t0 = LK0(kn2), t1 = LK1(kn2), t2 = LV0(kn2), t3 = LV1(kn2);
    STEP(ak0, ak1, av0, av1);            // compute kk (loads kk+2 in flight)
    int kn3 = ((kk + 3) & 31) << 5;
    half8 s0 = LK0(kn3), s1 = LK1(kn3), s2 = LV0(kn3), s3 = LV1(kn3);
    STEP(bk0, bk1, bv0, bv1);            // compute kk+1 (kk+3 in flight)
    ak0 = t0; ak1 = t1; av0 = t2; av1 = t3;
    bk0 = s0; bk1 = s1; bv0 = s2; bv1 = s3;
  }

  // normalize in-register (lsum for q=g*16+l16 sits on lane l16, reg 0),
  // pack fp16, store into LDS ctx tile: ctxL[q][wid*32 + dk]
  unsigned int* cL = (unsigned int*)ctxL;
#pragma unroll
  for (int g = 0; g < 4; ++g) {
    float linv = 1.0f / __shfl(Lacc[g][0], l16);
    int row = g * 16 + l16;
#pragma unroll
    for (int d = 0; d < 2; ++d) {
      int base = row * 140 + wid * 16 + d * 8 + quad * 2;
      cL[base]     = pk2(Ot[d][g][0] * linv, Ot[d][g][1] * linv);
      cL[base + 1] = pk2(Ot[d][g][2] * linv, Ot[d][g][3] * linv);
    }
  }
  __syncthreads();           // ctx tile complete AND Wo stage-0 resident

  // ---- oproj phase: out[64 x 256] = ctx @ Wo^T + bo, Wo streamed 4x64 cols
  int widm = wid >> 1, widn = wid & 1;   // 4 row-groups x 2 col-halves
  int tokbase = (b * 8 + p) * 1024 + qrow0;
  half8 a16[8];
#pragma unroll
  for (int ks = 0; ks < 8; ++ks)
    a16[ks] = *(const half8*)(ctxL + (widm * 16 + l16) * 280 + ks * 32 + quad * 8);

  for (int s = 0; s < 4; ++s) {
    if (s) __syncthreads();              // Wo stage s resident
    f32x4 acc[2] = {};
#pragma unroll
    for (int ks = 0; ks < 8; ++ks)
#pragma unroll
      for (int t = 0; t < 2; ++t) {
        half8 bf = *(const half8*)(Wb + ((size_t)((widn * 2 + t) * 8 + ks)) * 512 + lane * 8);
        acc[t] = mfma16(a16[ks], bf, acc[t]);
      }
    __syncthreads();                     // all waves done with Wb
    if (s < 3) {
#pragma unroll
      for (int it = 0; it < 4; ++it)
        g2lds16(WF3 + (size_t)(s + 1) * 16384 + it * 4096 + wid * 512 + lane * 8,
                Wb + it * 4096 + wid * 512);
    }
#pragma unroll
    for (int t = 0; t < 2; ++t) {
      int o = s * 64 + widn * 32 + t * 16 + l16;
      float bval = bo[o];
#pragma unroll
      for (int r = 0; r < 4; ++r)
        out[(size_t)(tokbase + widm * 16 + quad * 4 + r) * 256 + o] = acc[t][r] + bval;
    }
  }
}

extern "C" void kernel_launch(void* const* d_in, const int* in_sizes, int n_in,
                              void* d_out, int out_size, void* d_ws, size_t ws_size,
                              hipStream_t stream)
{
  const float* q  = (const float*)d_in[0];
  const float* k  = (const float*)d_in[1];
  const float* v  = (const float*)d_in[2];
  const float* Wq = (const float*)d_in[3];
  const float* bq = (const float*)d_in[4];
  const float* Wk = (const float*)d_in[5];
  const float* bk = (const float*)d_in[6];
  const float* Wv = (const float*)d_in[7];
  const float* bv = (const float*)d_in[8];
  const float* Wo = (const float*)d_in[9];
  const float* bo = (const float*)d_in[10];
  _Float16* ws = (_Float16*)d_ws;
  float* out = (float*)d_out;

  prep_kernel<<<128, 256, 0, stream>>>(Wq, Wk, Wv, Wo, ws);
  proj_kernel<<<dim3(256, 3), 256, 0, stream>>>(q, k, v, bq, bk, bv, ws);
  attno_kernel<<<256, 512, 0, stream>>>(ws, bo, out);   // 16 (b,p) x 16 qc
}